// Round 6
// baseline (130.092 us; speedup 1.0000x reference)
//
#include <hip/hip_runtime.h>

#define SS 512
#define NVERT (SS * SS)
#define ROWF (SS * 3)      // floats per row
#define NBATCH 16

struct V3 { float x, y, z; };

__device__ __forceinline__ float rsq_eps(float d) {
    // 1/max(sqrt(d),1e-12) == rsqrt(max(d,1e-24)); single v_rsq_f32
    return __builtin_amdgcn_rsqf(fmaxf(d, 1e-24f));
}

// accumulate unit normal of triangle (p0,p1,p2) into acc
__device__ __forceinline__ void addf(V3& acc, V3 p0, V3 p1, V3 p2) {
    float ux = p1.x - p0.x, uy = p1.y - p0.y, uz = p1.z - p0.z;
    float wx = p2.x - p0.x, wy = p2.y - p0.y, wz = p2.z - p0.z;
    float nx = uy * wz - uz * wy;
    float ny = uz * wx - ux * wz;
    float nz = ux * wy - uy * wx;
    float inv = rsq_eps(nx * nx + ny * ny + nz * nz);
    acc.x += nx * inv; acc.y += ny * inv; acc.z += nz * inv;
}

// Load 6 stencil points (cols 4t-1 .. 4t+4, clamped to [0,511]) of one row
// via aligned float4 window loads. p[j] <-> col clamp(4t-1+j).
__device__ __forceinline__ void load_row(const float* __restrict__ rowp, int t, V3 (&p)[6]) {
    if (t == 0) {
        const float4* w = reinterpret_cast<const float4*>(rowp);          // f[0..15]
        float4 a0 = w[0], a1 = w[1], a2 = w[2], a3 = w[3];
        p[1] = {a0.x, a0.y, a0.z};            // col 0
        p[0] = p[1];                          // col -1 -> clamp col 0
        p[2] = {a0.w, a1.x, a1.y};            // col 1
        p[3] = {a1.z, a1.w, a2.x};            // col 2
        p[4] = {a2.y, a2.z, a2.w};            // col 3
        p[5] = {a3.x, a3.y, a3.z};            // col 4
    } else {
        // window byte base 48t-16 (16B aligned); col 4t-1+j = floats 12t-3+3j..
        const float4* w = reinterpret_cast<const float4*>(rowp + 12 * t - 4);
        float4 a0 = w[0], a1 = w[1], a2 = w[2], a3 = w[3];
        p[0] = {a0.y, a0.z, a0.w};
        p[1] = {a1.x, a1.y, a1.z};
        p[2] = {a1.w, a2.x, a2.y};
        p[3] = {a2.z, a2.w, a3.x};
        p[4] = {a3.y, a3.z, a3.w};
        if (t < 127) {
            float4 a4 = w[4];
            p[5] = {a4.x, a4.y, a4.z};
        } else {
            p[5] = p[4];                      // col 512 -> clamp col 511
        }
    }
}

__global__ __launch_bounds__(256) void VertexNormals_kernel(
        const float* __restrict__ vrt, float* __restrict__ out) {
    int bid = blockIdx.x;
    // XCD-bijective swizzle: 4096 blocks, 8 XCDs -> each XCD a contiguous chunk
    int swz = ((bid & 7) << 9) | (bid >> 3);
    int tid = threadIdx.x;
    int t = tid & 127;                        // column group: cols 4t..4t+3
    int b = swz >> 8;                         // batch
    int r = ((swz & 255) << 1) | (tid >> 7);  // 2 rows per block

    const float* base = vrt + (size_t)b * (3 * NVERT);
    int rm1 = (r > 0) ? r - 1 : 0;
    int rp1 = (r < SS - 1) ? r + 1 : SS - 1;

    V3 A[6], B[6], C[6];                      // rows r-1, r, r+1
    load_row(base + (size_t)rm1 * ROWF, t, A);
    load_row(base + (size_t)r   * ROWF, t, B);
    load_row(base + (size_t)rp1 * ROWF, t, C);

    bool rm = (r > 0), rp = (r < SS - 1);

    float res[12];
    // Per-vertex enumeration — EXACTLY the R2-proven triangle sets/order,
    // fed from the window registers. Vertex i = col 4t+i <-> window j=i+1.
    #pragma unroll
    for (int i = 0; i < 4; ++i) {
        bool cm = (t > 0) || (i > 0);         // col > 0
        bool cp = (t < 127) || (i < 3);       // col < 511
        V3 pcm = B[i],     pcc = B[i + 1], pcp = B[i + 2];
        V3 pmc = A[i + 1], pmp = A[i + 2];
        V3 ppm = C[i],     ppc = C[i + 1];

        V3 acc = {0.f, 0.f, 0.f};
        if (rp && cp) addf(acc, pcc, ppc, pcp);                          // t1 @ (r,  c)
        if (rm && cp) { addf(acc, pmc, pcc, pmp); addf(acc, pmp, pcc, pcp); } // quad (r-1,c) t1,t2
        if (rp && cm) { addf(acc, pcm, ppm, pcc); addf(acc, pcc, ppm, ppc); } // quad (r,c-1) t1,t2
        if (rm && cm) addf(acc, pmc, pcm, pcc);                          // quad (r-1,c-1) t2

        float inv = rsq_eps(acc.x * acc.x + acc.y * acc.y + acc.z * acc.z);
        res[3 * i + 0] = acc.x * inv;
        res[3 * i + 1] = acc.y * inv;
        res[3 * i + 2] = acc.z * inv;
    }

    float* o = out + ((size_t)b * NVERT + (size_t)r * SS + 4 * (size_t)t) * 3;
    reinterpret_cast<float4*>(o)[0] = {res[0], res[1], res[2],  res[3]};
    reinterpret_cast<float4*>(o)[1] = {res[4], res[5], res[6],  res[7]};
    reinterpret_cast<float4*>(o)[2] = {res[8], res[9], res[10], res[11]};
}

extern "C" void kernel_launch(void* const* d_in, const int* in_sizes, int n_in,
                              void* d_out, int out_size, void* d_ws, size_t ws_size,
                              hipStream_t stream) {
    const float* vrt = (const float*)d_in[0];   // (16, 512*512, 3) fp32
    float* out = (float*)d_out;                 // (16, 512*512, 3) fp32

    const int grid = (NBATCH * SS) / 2;         // 4096 blocks: 2 rows x 128 col-groups
    hipLaunchKernelGGL(VertexNormals_kernel, dim3(grid), dim3(256), 0, stream,
                       vrt, out);
}

// Round 7
// 126.368 us; speedup vs baseline: 1.0295x; 1.0295x over previous
//
#include <hip/hip_runtime.h>

#define SS 512
#define NVERT (SS * SS)
#define ROWF (SS * 3)      // floats per row
#define NBATCH 16

struct V3 { float x, y, z; };

__device__ __forceinline__ float rsq_eps(float d) {
    // 1/max(sqrt(d),1e-12) == rsqrt(max(d,1e-24)); single v_rsq_f32
    return __builtin_amdgcn_rsqf(fmaxf(d, 1e-24f));
}

// accumulate unit normal of triangle (p0,p1,p2) into acc
__device__ __forceinline__ void addf(V3& acc, V3 p0, V3 p1, V3 p2) {
    float ux = p1.x - p0.x, uy = p1.y - p0.y, uz = p1.z - p0.z;
    float wx = p2.x - p0.x, wy = p2.y - p0.y, wz = p2.z - p0.z;
    float nx = uy * wz - uz * wy;
    float ny = uz * wx - ux * wz;
    float nz = ux * wy - uy * wx;
    float inv = rsq_eps(nx * nx + ny * ny + nz * nz);
    acc.x += nx * inv; acc.y += ny * inv; acc.z += nz * inv;
}

// Load 6 stencil points (cols 4t-1 .. 4t+4, clamped to [0,511]) of one row
// via aligned float4 window loads. p[j] <-> col clamp(4t-1+j).
__device__ __forceinline__ void load_row(const float* __restrict__ rowp, int t, V3 (&p)[6]) {
    if (t == 0) {
        const float4* w = reinterpret_cast<const float4*>(rowp);          // f[0..15]
        float4 a0 = w[0], a1 = w[1], a2 = w[2], a3 = w[3];
        p[1] = {a0.x, a0.y, a0.z};            // col 0
        p[0] = p[1];                          // col -1 -> clamp col 0
        p[2] = {a0.w, a1.x, a1.y};            // col 1
        p[3] = {a1.z, a1.w, a2.x};            // col 2
        p[4] = {a2.y, a2.z, a2.w};            // col 3
        p[5] = {a3.x, a3.y, a3.z};            // col 4
    } else {
        // window byte base 48t-16 (16B aligned); col 4t-1+j = floats 12t-3+3j..
        const float4* w = reinterpret_cast<const float4*>(rowp + 12 * t - 4);
        float4 a0 = w[0], a1 = w[1], a2 = w[2], a3 = w[3];
        p[0] = {a0.y, a0.z, a0.w};
        p[1] = {a1.x, a1.y, a1.z};
        p[2] = {a1.w, a2.x, a2.y};
        p[3] = {a2.z, a2.w, a3.x};
        p[4] = {a3.y, a3.z, a3.w};
        if (t < 127) {
            float4 a4 = w[4];
            p[5] = {a4.x, a4.y, a4.z};
        } else {
            p[5] = p[4];                      // col 512 -> clamp col 511
        }
    }
}

// R6-proven per-vertex enumeration for one output row.
// A = row r-1 (clamped), B = row r, C = row r+1 (clamped).
__device__ __forceinline__ void compute_row(const V3 (&A)[6], const V3 (&B)[6], const V3 (&C)[6],
                                            bool rm, bool rp, int t, float (&res)[12]) {
    #pragma unroll
    for (int i = 0; i < 4; ++i) {
        bool cm = (t > 0) || (i > 0);         // col > 0
        bool cp = (t < 127) || (i < 3);       // col < 511
        V3 pcm = B[i],     pcc = B[i + 1], pcp = B[i + 2];
        V3 pmc = A[i + 1], pmp = A[i + 2];
        V3 ppm = C[i],     ppc = C[i + 1];

        V3 acc = {0.f, 0.f, 0.f};
        if (rp && cp) addf(acc, pcc, ppc, pcp);                               // t1 @ (r,  c)
        if (rm && cp) { addf(acc, pmc, pcc, pmp); addf(acc, pmp, pcc, pcp); } // quad (r-1,c) t1,t2
        if (rp && cm) { addf(acc, pcm, ppm, pcc); addf(acc, pcc, ppm, ppc); } // quad (r,c-1) t1,t2
        if (rm && cm) addf(acc, pmc, pcm, pcc);                               // quad (r-1,c-1) t2

        float inv = rsq_eps(acc.x * acc.x + acc.y * acc.y + acc.z * acc.z);
        res[3 * i + 0] = acc.x * inv;
        res[3 * i + 1] = acc.y * inv;
        res[3 * i + 2] = acc.z * inv;
    }
}

__global__ __launch_bounds__(256) void VertexNormals_kernel(
        const float* __restrict__ vrt, float* __restrict__ out) {
    int bid = blockIdx.x;
    // XCD-bijective swizzle: 2048 blocks, 8 XCDs, 256 contiguous chunks each
    int swz = ((bid & 7) << 8) | (bid >> 3);
    int tid = threadIdx.x;
    int t = tid & 127;                        // column group: cols 4t..4t+3
    int h = tid >> 7;                         // row-pair within block
    int b = swz >> 7;                         // batch
    int rq = swz & 127;                       // row-quad
    int r0 = (rq << 2) | (h << 1);            // even row in [0,510]
    int r1 = r0 + 1;

    const float* base = vrt + (size_t)b * (3 * NVERT);
    int rmi = (r0 > 0)      ? r0 - 1 : 0;
    int rpi = (r1 < SS - 1) ? r1 + 1 : SS - 1;

    // 4 stencil rows, 20 independent float4 loads issued up-front
    V3 A[6], B[6], C[6], D[6];
    load_row(base + (size_t)rmi * ROWF, t, A);
    load_row(base + (size_t)r0  * ROWF, t, B);
    load_row(base + (size_t)r1  * ROWF, t, C);
    load_row(base + (size_t)rpi * ROWF, t, D);

    float res0[12], res1[12];
    compute_row(A, B, C, (r0 > 0), true, t, res0);           // row r0 (r0 <= 510)
    compute_row(B, C, D, true, (r1 < SS - 1), t, res1);      // row r1 (r1 >= 1)

    float* o0 = out + ((size_t)b * NVERT + (size_t)r0 * SS + 4 * (size_t)t) * 3;
    float* o1 = o0 + ROWF;
    reinterpret_cast<float4*>(o0)[0] = {res0[0], res0[1], res0[2],  res0[3]};
    reinterpret_cast<float4*>(o0)[1] = {res0[4], res0[5], res0[6],  res0[7]};
    reinterpret_cast<float4*>(o0)[2] = {res0[8], res0[9], res0[10], res0[11]};
    reinterpret_cast<float4*>(o1)[0] = {res1[0], res1[1], res1[2],  res1[3]};
    reinterpret_cast<float4*>(o1)[1] = {res1[4], res1[5], res1[6],  res1[7]};
    reinterpret_cast<float4*>(o1)[2] = {res1[8], res1[9], res1[10], res1[11]};
}

extern "C" void kernel_launch(void* const* d_in, const int* in_sizes, int n_in,
                              void* d_out, int out_size, void* d_ws, size_t ws_size,
                              hipStream_t stream) {
    const float* vrt = (const float*)d_in[0];   // (16, 512*512, 3) fp32
    float* out = (float*)d_out;                 // (16, 512*512, 3) fp32

    const int grid = (NBATCH * SS) / 4;         // 2048 blocks: 4 rows x 128 col-groups
    hipLaunchKernelGGL(VertexNormals_kernel, dim3(grid), dim3(256), 0, stream,
                       vrt, out);
}

// Round 8
// 121.016 us; speedup vs baseline: 1.0750x; 1.0442x over previous
//
#include <hip/hip_runtime.h>

#define SS 512
#define NVERT (SS * SS)
#define ROWF (SS * 3)          // 1536 floats per row
#define ROWC (SS * 3 / 4)      // 384 float4 chunks per row
#define NBATCH 16
#define SROWS 6                // staged rows per block
#define NCHUNK (SROWS * ROWC)  // 2304 chunks = 36 KiB LDS

struct V3 { float x, y, z; };

typedef const __attribute__((address_space(1))) void gv_t;
typedef __attribute__((address_space(3))) void lv_t;

__device__ __forceinline__ float rsq_eps(float d) {
    // 1/max(sqrt(d),1e-12) == rsqrt(max(d,1e-24)); single v_rsq_f32
    return __builtin_amdgcn_rsqf(fmaxf(d, 1e-24f));
}

// accumulate unit normal of triangle (p0,p1,p2) into acc
__device__ __forceinline__ void addf(V3& acc, V3 p0, V3 p1, V3 p2) {
    float ux = p1.x - p0.x, uy = p1.y - p0.y, uz = p1.z - p0.z;
    float wx = p2.x - p0.x, wy = p2.y - p0.y, wz = p2.z - p0.z;
    float nx = uy * wz - uz * wy;
    float ny = uz * wx - ux * wz;
    float nz = ux * wy - uy * wx;
    float inv = rsq_eps(nx * nx + ny * ny + nz * nz);
    acc.x += nx * inv; acc.y += ny * inv; acc.z += nz * inv;
}

// Extract 6-col window (cols 4t-1..4t+4, clamped) of one staged row from LDS.
// ldsrow points at the row's 384 chunks; chunk reads are ds_read_b128,
// lane stride 3 chunks (gcd(3,8)=1 -> uniform bank-group coverage).
__device__ __forceinline__ void load_row_lds(const float4* __restrict__ ldsrow, int t, V3 (&p)[6]) {
    if (t == 0) {
        float4 a0 = ldsrow[0], a1 = ldsrow[1], a2 = ldsrow[2], a3 = ldsrow[3];
        p[1] = {a0.x, a0.y, a0.z};            // col 0
        p[0] = p[1];                          // col -1 -> clamp col 0
        p[2] = {a0.w, a1.x, a1.y};
        p[3] = {a1.z, a1.w, a2.x};
        p[4] = {a2.y, a2.z, a2.w};
        p[5] = {a3.x, a3.y, a3.z};
    } else {
        const float4* w = ldsrow + 3 * t - 1; // float offset 12t-4, 16B aligned
        float4 a0 = w[0], a1 = w[1], a2 = w[2], a3 = w[3];
        p[0] = {a0.y, a0.z, a0.w};
        p[1] = {a1.x, a1.y, a1.z};
        p[2] = {a1.w, a2.x, a2.y};
        p[3] = {a2.z, a2.w, a3.x};
        p[4] = {a3.y, a3.z, a3.w};
        if (t < 127) {
            float4 a4 = w[4];
            p[5] = {a4.x, a4.y, a4.z};
        } else {
            p[5] = p[4];                      // col 512 -> clamp col 511
        }
    }
}

__global__ __launch_bounds__(512) void VertexNormals_kernel(
        const float* __restrict__ vrt, float* __restrict__ out) {
    __shared__ float4 smem[NCHUNK];

    int bid = blockIdx.x;
    // XCD-bijective swizzle: 2048 blocks, 8 XCDs, 256 contiguous chunks each
    int swz = ((bid & 7) << 8) | (bid >> 3);
    int tid = threadIdx.x;
    int b  = swz >> 7;                        // batch
    int rb = swz & 127;                       // row-block (4 rows each)
    int r0 = rb << 2;
    int rs = r0 - 1;                          // staged-row start, clamped to [0,506]
    rs = rs < 0 ? 0 : (rs > (SS - SROWS) ? (SS - SROWS) : rs);

    // ---- Stage 6 contiguous rows (36 KB) via global_load_lds, zero VGPR in flight
    const float4* gsrc = reinterpret_cast<const float4*>(
        vrt + (size_t)b * (3 * NVERT) + (size_t)rs * ROWF);
    #pragma unroll
    for (int i = 0; i < 4; ++i) {
        int idx = tid + 512 * i;
        __builtin_amdgcn_global_load_lds((gv_t*)(gsrc + idx), (lv_t*)(&smem[idx]), 16, 0, 0);
    }
    if (tid < 256) {                          // remainder: chunks 2048..2303 (waves 0-3, no intra-wave divergence)
        int idx = tid + 2048;
        __builtin_amdgcn_global_load_lds((gv_t*)(gsrc + idx), (lv_t*)(&smem[idx]), 16, 0, 0);
    }
    __syncthreads();                          // drains vmcnt; staged data visible

    // ---- Compute: 1 output row per thread, proven per-vertex enumeration
    int t = tid & 127;                        // column group: cols 4t..4t+3
    int h = tid >> 7;                         // 0..3
    int r = r0 + h;
    int la = ((r > 0) ? r - 1 : 0) - rs;      // local staged-row indices, all in [0,5]
    int lb = r - rs;
    int lc = ((r < SS - 1) ? r + 1 : SS - 1) - rs;

    V3 A[6], B[6], C[6];
    load_row_lds(smem + la * ROWC, t, A);
    load_row_lds(smem + lb * ROWC, t, B);
    load_row_lds(smem + lc * ROWC, t, C);

    bool rm = (r > 0), rp = (r < SS - 1);

    float res[12];
    #pragma unroll
    for (int i = 0; i < 4; ++i) {
        bool cm = (t > 0) || (i > 0);         // col > 0
        bool cp = (t < 127) || (i < 3);       // col < 511
        V3 pcm = B[i],     pcc = B[i + 1], pcp = B[i + 2];
        V3 pmc = A[i + 1], pmp = A[i + 2];
        V3 ppm = C[i],     ppc = C[i + 1];

        V3 acc = {0.f, 0.f, 0.f};
        if (rp && cp) addf(acc, pcc, ppc, pcp);                               // t1 @ (r,  c)
        if (rm && cp) { addf(acc, pmc, pcc, pmp); addf(acc, pmp, pcc, pcp); } // quad (r-1,c) t1,t2
        if (rp && cm) { addf(acc, pcm, ppm, pcc); addf(acc, pcc, ppm, ppc); } // quad (r,c-1) t1,t2
        if (rm && cm) addf(acc, pmc, pcm, pcc);                               // quad (r-1,c-1) t2

        float inv = rsq_eps(acc.x * acc.x + acc.y * acc.y + acc.z * acc.z);
        res[3 * i + 0] = acc.x * inv;
        res[3 * i + 1] = acc.y * inv;
        res[3 * i + 2] = acc.z * inv;
    }

    float* o = out + ((size_t)b * NVERT + (size_t)r * SS + 4 * (size_t)t) * 3;
    reinterpret_cast<float4*>(o)[0] = {res[0], res[1], res[2],  res[3]};
    reinterpret_cast<float4*>(o)[1] = {res[4], res[5], res[6],  res[7]};
    reinterpret_cast<float4*>(o)[2] = {res[8], res[9], res[10], res[11]};
}

extern "C" void kernel_launch(void* const* d_in, const int* in_sizes, int n_in,
                              void* d_out, int out_size, void* d_ws, size_t ws_size,
                              hipStream_t stream) {
    const float* vrt = (const float*)d_in[0];   // (16, 512*512, 3) fp32
    float* out = (float*)d_out;                 // (16, 512*512, 3) fp32

    const int grid = (NBATCH * SS) / 4;         // 2048 blocks: 4 output rows x 512 cols each
    hipLaunchKernelGGL(VertexNormals_kernel, dim3(grid), dim3(512), 0, stream,
                       vrt, out);
}

// Round 9
// 120.329 us; speedup vs baseline: 1.0811x; 1.0057x over previous
//
#include <hip/hip_runtime.h>

#define SS 512
#define NVERT (SS * SS)
#define ROWF (SS * 3)          // 1536 floats per row
#define ROWC (SS * 3 / 4)      // 384 float4 chunks per row
#define NBATCH 16
#define SROWS 6                // staged rows per block
#define NCHUNK (SROWS * ROWC)  // 2304 chunks = 36 KiB LDS

struct V3 { float x, y, z; };

typedef const __attribute__((address_space(1))) void gv_t;
typedef __attribute__((address_space(3))) void lv_t;

__device__ __forceinline__ float rsq_eps(float d) {
    // 1/max(sqrt(d),1e-12) == rsqrt(max(d,1e-24)); single v_rsq_f32
    return __builtin_amdgcn_rsqf(fmaxf(d, 1e-24f));
}

// unit normal of triangle (p0,p1,p2).
// NOTE: under fma contraction, cross is EXACTLY zero only for the u==0
// (p0==p1) and w==0 (p0==p2) degeneracies. p1==p2 leaves an fma rounding
// residue that normalizes to a garbage UNIT vector (the R5 bug) — those
// three boundary cases are explicitly zeroed by the caller.
__device__ __forceinline__ V3 facen(V3 p0, V3 p1, V3 p2) {
    float ux = p1.x - p0.x, uy = p1.y - p0.y, uz = p1.z - p0.z;
    float wx = p2.x - p0.x, wy = p2.y - p0.y, wz = p2.z - p0.z;
    float nx = uy * wz - uz * wy;
    float ny = uz * wx - ux * wz;
    float nz = ux * wy - uy * wx;
    float inv = rsq_eps(nx * nx + ny * ny + nz * nz);
    return {nx * inv, ny * inv, nz * inv};
}

// Extract 6-col window (cols 4t-1..4t+4, clamped) of one staged row from LDS.
__device__ __forceinline__ void load_row_lds(const float4* __restrict__ ldsrow, int t, V3 (&p)[6]) {
    if (t == 0) {
        float4 a0 = ldsrow[0], a1 = ldsrow[1], a2 = ldsrow[2], a3 = ldsrow[3];
        p[1] = {a0.x, a0.y, a0.z};            // col 0
        p[0] = p[1];                          // col -1 -> clamp col 0
        p[2] = {a0.w, a1.x, a1.y};
        p[3] = {a1.z, a1.w, a2.x};
        p[4] = {a2.y, a2.z, a2.w};
        p[5] = {a3.x, a3.y, a3.z};
    } else {
        const float4* w = ldsrow + 3 * t - 1; // float offset 12t-4, 16B aligned
        float4 a0 = w[0], a1 = w[1], a2 = w[2], a3 = w[3];
        p[0] = {a0.y, a0.z, a0.w};
        p[1] = {a1.x, a1.y, a1.z};
        p[2] = {a1.w, a2.x, a2.y};
        p[3] = {a2.z, a2.w, a3.x};
        p[4] = {a3.y, a3.z, a3.w};
        if (t < 127) {
            float4 a4 = w[4];
            p[5] = {a4.x, a4.y, a4.z};
        } else {
            p[5] = p[4];                      // col 512 -> clamp col 511
        }
    }
}

__global__ __launch_bounds__(512) void VertexNormals_kernel(
        const float* __restrict__ vrt, float* __restrict__ out) {
    __shared__ float4 smem[NCHUNK];

    int bid = blockIdx.x;
    // XCD-bijective swizzle: 2048 blocks, 8 XCDs, 256 contiguous chunks each
    int swz = ((bid & 7) << 8) | (bid >> 3);
    int tid = threadIdx.x;
    int b  = swz >> 7;                        // batch
    int rb = swz & 127;                       // row-block (4 rows each)
    int r0 = rb << 2;
    int rs = r0 - 1;                          // staged-row start, clamped to [0,506]
    rs = rs < 0 ? 0 : (rs > (SS - SROWS) ? (SS - SROWS) : rs);

    // ---- Stage 6 contiguous rows (36 KB) via global_load_lds, zero VGPR in flight
    const float4* gsrc = reinterpret_cast<const float4*>(
        vrt + (size_t)b * (3 * NVERT) + (size_t)rs * ROWF);
    #pragma unroll
    for (int i = 0; i < 4; ++i) {
        int idx = tid + 512 * i;
        __builtin_amdgcn_global_load_lds((gv_t*)(gsrc + idx), (lv_t*)(&smem[idx]), 16, 0, 0);
    }
    if (tid < 256) {                          // remainder chunks 2048..2303 (waves 0-3)
        int idx = tid + 2048;
        __builtin_amdgcn_global_load_lds((gv_t*)(gsrc + idx), (lv_t*)(&smem[idx]), 16, 0, 0);
    }
    __syncthreads();                          // drains vmcnt; staged data visible

    // ---- Compute: 1 output row per thread, shared-face-normal enumeration
    int t = tid & 127;                        // column group: cols 4t..4t+3
    int h = tid >> 7;                         // 0..3
    int r = r0 + h;
    int la = ((r > 0) ? r - 1 : 0) - rs;      // local staged-row indices in [0,5]
    int lb = r - rs;
    int lc = ((r < SS - 1) ? r + 1 : SS - 1) - rs;

    V3 A[6], B[6], C[6];
    load_row_lds(smem + la * ROWC, t, A);
    load_row_lds(smem + lb * ROWC, t, B);
    load_row_lds(smem + lc * ROWC, t, C);

    const V3 Z = {0.f, 0.f, 0.f};

    // Shared normals across the 4 vertices of this row strip.
    // Quad q has quad-col 4t-1+q. Band U = quad row r-1, band L = quad row r.
    //   ut2[q] = U-band t2 = (A[q+1], B[q], B[q+1])   used by vertices q-1, q
    //   lt1[q] = L-band t1 = (B[q],  C[q], B[q+1])    used by vertices q-1, q
    // Boundary-excluded triangles are exact-zero via u==0/w==0 degeneracy,
    // EXCEPT the p1==p2 cases below which must be zeroed explicitly.
    V3 ut2[5], lt1[5];
    #pragma unroll
    for (int q = 0; q < 5; ++q) {
        ut2[q] = facen(A[q + 1], B[q], B[q + 1]);
        lt1[q] = facen(B[q],     C[q], B[q + 1]);
    }
    if (t == 0)   ut2[0] = Z;                 // quad col -1: p1==p2 residue
    if (t == 127) ut2[4] = Z;                 // quad col 511: p1==p2 residue

    float res[12];
    #pragma unroll
    for (int i = 0; i < 4; ++i) {
        V3 u1 = facen(A[i + 1], B[i + 1], A[i + 2]);  // upper t1, quad q=i+1
        V3 l2 = facen(B[i + 1], C[i],     C[i + 1]);  // lower t2, quad q=i
        if (i == 0 && t == 0) l2 = Z;                 // quad col -1: p1==p2 residue

        float ax = u1.x + l2.x + ut2[i].x + ut2[i + 1].x + lt1[i].x + lt1[i + 1].x;
        float ay = u1.y + l2.y + ut2[i].y + ut2[i + 1].y + lt1[i].y + lt1[i + 1].y;
        float az = u1.z + l2.z + ut2[i].z + ut2[i + 1].z + lt1[i].z + lt1[i + 1].z;

        float inv = rsq_eps(ax * ax + ay * ay + az * az);
        res[3 * i + 0] = ax * inv;
        res[3 * i + 1] = ay * inv;
        res[3 * i + 2] = az * inv;
    }

    float* o = out + ((size_t)b * NVERT + (size_t)r * SS + 4 * (size_t)t) * 3;
    reinterpret_cast<float4*>(o)[0] = {res[0], res[1], res[2],  res[3]};
    reinterpret_cast<float4*>(o)[1] = {res[4], res[5], res[6],  res[7]};
    reinterpret_cast<float4*>(o)[2] = {res[8], res[9], res[10], res[11]};
}

extern "C" void kernel_launch(void* const* d_in, const int* in_sizes, int n_in,
                              void* d_out, int out_size, void* d_ws, size_t ws_size,
                              hipStream_t stream) {
    const float* vrt = (const float*)d_in[0];   // (16, 512*512, 3) fp32
    float* out = (float*)d_out;                 // (16, 512*512, 3) fp32

    const int grid = (NBATCH * SS) / 4;         // 2048 blocks: 4 output rows x 512 cols
    hipLaunchKernelGGL(VertexNormals_kernel, dim3(grid), dim3(512), 0, stream,
                       vrt, out);
}